// Round 9
// baseline (595.471 us; speedup 1.0000x reference)
//
#include <hip/hip_runtime.h>
#include <hip/hip_cooperative_groups.h>
#include <math.h>

namespace cg = cooperative_groups;

// Problem constants
#define NM 20301            // mesh points
#define TT 4096             // time steps
#define NC 16               // t-chunks
#define CH 256              // steps per chunk
#define NW 318              // 64-n wave tasks: ceil(NM/64)
#define NMP (NW * 64)       // 20352
#define NTASK (NW * NC)     // 5088 states wave-tasks
#define NBLOCKS 256
#define NTH 1024
#define LOG2E_K 1442.69504f // 1000 * log2(e)  (temp = 0.001)
#define WNEAR 26.0f         // saturation cutoff (|z|>=18 natural units)

// Fused soft-relay step (slow path): one rcp instead of two.
__device__ __forceinline__ void relay_step(float ka, float kb, float ku,
                                           float& aa, float& bb) {
    float z1 = fminf(ka - ku, 63.f);
    float z2 = fminf(ku - kb, 63.f);
    float e1 = __builtin_amdgcn_exp2f(z1);
    float e2 = __builtin_amdgcn_exp2f(z2);
    float p1 = 1.f + e1, p2 = 1.f + e2;
    float r  = __builtin_amdgcn_rcpf(p1 * p2);
    aa = (e2 - e1) * r;
    bb = (e1 * e2) * r;
}

__device__ __forceinline__ float wave_reduce_sum(float w) {
    #pragma unroll
    for (int off = 32; off > 0; off >>= 1)
        w += __shfl_down(w, off, 64);
    return w;
}

// One cooperative kernel: A density+s0 | B compose | sync | D mini-scan +
// states + per-wave reduce | sync | E finalize. 256 blocks x 1024 threads,
// 1 block/CU co-resident (LDS 52 KB, VGPR capped by launch_bounds).
__global__ __launch_bounds__(NTH, 4) void mega_kernel(
    const float* __restrict__ x, const float* __restrict__ alpha,
    const float* __restrict__ beta, const float* __restrict__ init_raw,
    const float* __restrict__ msr, const float* __restrict__ mor,
    const float* __restrict__ hsr,
    const float* __restrict__ w1, const float* __restrict__ b1,
    const float* __restrict__ w2, const float* __restrict__ b2,
    const float* __restrict__ w3, const float* __restrict__ b3,
    const float* __restrict__ w4, const float* __restrict__ b4,
    float* __restrict__ out, float* __restrict__ density,
    float* __restrict__ states,
    float* __restrict__ Ag, float* __restrict__ Bg,
    float* __restrict__ wpart, float* __restrict__ s0g,
    float* __restrict__ dparts)
{
    __shared__ float xall[TT];              // 16 KB: all of x, pre-scaled
    __shared__ float tiles[16 * 64 * 9];    // 36.9 KB: per-wave reduce tiles

    cg::grid_group grid = cg::this_grid();
    int b = blockIdx.x, tid = threadIdx.x;
    int ln = tid & 63, wv = tid >> 6;
    int g = b * NTH + tid;

    for (int q = tid; q < TT; q += NTH) xall[q] = x[q] * LOG2E_K;
    __syncthreads();

    // ---- phase A: density MLP + s0 = tanh(init) + densum wave-partials ----
    if (g < NMP) {
        bool valid = g < NM;
        int nn = valid ? g : NM - 1;
        float a = alpha[nn], bb_ = beta[nn];
        float h1[16], h2[16], h3[16];
        #pragma unroll
        for (int j = 0; j < 16; j++) {
            float v = fmaf(a, w1[j], fmaf(bb_, w1[16 + j], b1[j]));
            h1[j] = fmaxf(v, 0.f);
        }
        #pragma unroll
        for (int j = 0; j < 16; j++) {
            float v = b2[j];
            #pragma unroll
            for (int k = 0; k < 16; k++) v = fmaf(h1[k], w2[k * 16 + j], v);
            h2[j] = fmaxf(v, 0.f);
        }
        #pragma unroll
        for (int j = 0; j < 16; j++) {
            float v = b3[j];
            #pragma unroll
            for (int k = 0; k < 16; k++) v = fmaf(h2[k], w3[k * 16 + j], v);
            h3[j] = fmaxf(v, 0.f);
        }
        float v = b4[0];
        #pragma unroll
        for (int k = 0; k < 16; k++) v = fmaf(h3[k], w4[k], v);
        float d = 1.f / (1.f + __expf(-v));
        if (valid) { density[g] = d; s0g[g] = tanhf(init_raw[g]); }
        float wsum = wave_reduce_sum(valid ? d : 0.f);
        if (ln == 0) dparts[g >> 6] = wsum;
    }

    // ---- phase B: chunk composites (A,B) per (n, c); NC*NMP tasks -------
    #pragma unroll
    for (int rep = 0; rep < 2; rep++) {
        int idx = g + rep * (NBLOCKS * NTH);
        if (idx < NC * NMP) {
            int c = idx / NMP;
            int n = idx - c * NMP;
            int nn = (n < NM) ? n : NM - 1;
            float ka = alpha[nn] * LOG2E_K;
            float kb = beta[nn] * LOG2E_K;
            float A = 0.f, Bv = 1.f;
            const float* xc = &xall[c * CH];
            #pragma unroll 8
            for (int i = 0; i < CH; i++) {
                float u = xc[i];
                float d1 = ka - u, d2 = u - kb;
                bool nearb = fminf(fabsf(d1), fabsf(d2)) < WNEAR;
                if (__any(nearb)) {              // wave-uniform branch
                    float aa, bb;
                    relay_step(ka, kb, u, aa, bb);
                    A = fmaf(bb, A, aa);
                    Bv *= bb;
                } else {
                    bool su = d1 < 0.f, sd = d2 < 0.f;
                    A  = su ? 1.f : (sd ? -1.f : A);
                    Bv = (su || sd) ? 0.f : Bv;
                }
            }
            if (n < NM) { Ag[c * NM + n] = A; Bg[c * NM + n] = Bv; }
        }
    }

    grid.sync();

    // ---- phase D: states. Waves grid-stride over 5088 (64n x 256t) tasks;
    // block b owns tasks [b*5088/256, (b+1)*5088/256) -> 19-20 per CU,
    // balanced. Each task: 16-step mini-scan (from Ag/Bg) then 256-step
    // replay, column-coalesced stores, per-wave LDS-tile d*s reduction.
    {
        int t0 = (b * NTASK) >> 8;
        int t1 = ((b + 1) * NTASK) >> 8;
        float* wt = &tiles[wv * 576];
        float* ts = &wt[ln * 9];
        int tl = ln & 7, g8 = ln >> 3;
        for (int w = t0 + wv; w < t1; w += 16) {
            int c = w / NW, nblk = w - c * NW;
            int n = nblk * 64 + ln;
            bool valid = n < NM;
            int nn = valid ? n : NM - 1;
            float ka = alpha[nn] * LOG2E_K;
            float kb = beta[nn] * LOG2E_K;
            float d  = valid ? density[nn] : 0.f;
            float s  = s0g[nn];
            for (int cc = 0; cc < c; cc++)       // mini-scan to chunk start
                s = fmaf(Bg[cc * NM + nn], s, Ag[cc * NM + nn]);
            const float* xc = &xall[c * CH];
            float* rowp = states + (size_t)c * CH * NM + n;
            size_t wp = (size_t)w * CH;
            for (int p = 0; p < 32; p++) {
                #pragma unroll
                for (int j = 0; j < 8; j++) {
                    int i = p * 8 + j;
                    float u = xc[i];
                    float d1 = ka - u, d2 = u - kb;
                    bool nearb = fminf(fabsf(d1), fabsf(d2)) < WNEAR;
                    if (__any(nearb)) {
                        float aa, bb;
                        relay_step(ka, kb, u, aa, bb);
                        s = fmaf(bb, s, aa);
                    } else {
                        s = (d1 < 0.f) ? 1.f : ((d2 < 0.f) ? -1.f : s);
                    }
                    if (valid) rowp[(size_t)i * NM] = s;
                    ts[j] = d * s;               // fire-and-forget ds_write
                }
                asm volatile("s_waitcnt lgkmcnt(0)" ::: "memory");
                float acc = 0.f;
                #pragma unroll
                for (int k = 0; k < 8; k++)       // banks (9k+ln)%32: 2-way
                    acc += wt[(g8 * 8 + k) * 9 + tl];
                acc += __shfl_xor(acc, 8, 64);    // fold 8 n-groups
                acc += __shfl_xor(acc, 16, 64);
                acc += __shfl_xor(acc, 32, 64);
                if (ln < 8) wpart[wp + p * 8 + ln] = acc;
                asm volatile("s_waitcnt lgkmcnt(0)" ::: "memory");  // WAR
            }
        }
    }

    grid.sync();

    // ---- phase E: finalize out[t] ----------------------------------------
    if (g < TT) {
        int c = g >> 8, i = g & 255;
        float acc = 0.f;
        for (int nb = 0; nb < NW; nb++)
            acc += wpart[((size_t)(c * NW + nb)) * CH + i];  // lane-coalesced
        float dsum = 0.f;
        for (int nb = 0; nb < NW; nb++) dsum += dparts[nb];  // uniform
        float sig_ms = 1.f / (1.f + __expf(-msr[0]));
        float sig_mo = 1.f / (1.f + __expf(-mor[0]));
        float sig_hs = 1.f / (1.f + __expf(-hsr[0]));
        float m_scale  = 10.f * sig_ms;
        float m_offset = fmaf(20.f, sig_mo, -10.f);
        float h_scale  = 10.f * sig_hs;
        float m = acc / dsum;
        out[g] = fmaf(m_scale, m, m_offset) + h_scale * x[g];
    }
}

extern "C" void kernel_launch(void* const* d_in, const int* in_sizes, int n_in,
                              void* d_out, int out_size, void* d_ws, size_t ws_size,
                              hipStream_t stream)
{
    const float* x    = (const float*)d_in[0];
    const float* alpha= (const float*)d_in[1];
    const float* beta = (const float*)d_in[2];
    const float* init = (const float*)d_in[3];
    const float* msr  = (const float*)d_in[4];
    const float* mor  = (const float*)d_in[5];
    const float* hsr  = (const float*)d_in[6];
    const float* w1   = (const float*)d_in[7];
    const float* b1   = (const float*)d_in[8];
    const float* w2   = (const float*)d_in[9];
    const float* b2   = (const float*)d_in[10];
    const float* w3   = (const float*)d_in[11];
    const float* b3   = (const float*)d_in[12];
    const float* w4   = (const float*)d_in[13];
    const float* b4   = (const float*)d_in[14];

    float* out     = (float*)d_out;          // [TT]
    float* density = out + TT;               // [NM]
    float* states  = density + NM;           // [TT*NM]

    // ws: Ag[NC*NM] | Bg[NC*NM] | wpart[NTASK*CH] | s0g[NM] | dparts[NW]
    float* Ag     = (float*)d_ws;
    float* Bg     = Ag + NC * NM;
    float* wpart  = Bg + NC * NM;
    float* s0g    = wpart + (size_t)NTASK * CH;
    float* dparts = s0g + NM + 64;

    void* args[] = {
        (void*)&x, (void*)&alpha, (void*)&beta, (void*)&init,
        (void*)&msr, (void*)&mor, (void*)&hsr,
        (void*)&w1, (void*)&b1, (void*)&w2, (void*)&b2,
        (void*)&w3, (void*)&b3, (void*)&w4, (void*)&b4,
        (void*)&out, (void*)&density, (void*)&states,
        (void*)&Ag, (void*)&Bg, (void*)&wpart, (void*)&s0g, (void*)&dparts
    };
    hipLaunchCooperativeKernel((void*)mega_kernel, dim3(NBLOCKS), dim3(NTH),
                               args, 0, stream);
}

// Round 10
// 455.217 us; speedup vs baseline: 1.3081x; 1.3081x over previous
//
#include <hip/hip_runtime.h>
#include <math.h>

// Problem constants
#define NM 20301            // mesh points
#define TT 4096             // time steps
#define NC 32               // t-chunks
#define CH 128              // steps per chunk = TT/NC
#define NBLK 80             // 256-thread n-kernels (density/compose/scan)
#define SBLK 40             // states blocks in n (512 n per block, 2/thread)
#define NPROW (SBLK * 4)    // 160 per-wave partial rows
#define TPH 16              // t-phase width for fused reduce
#define NPH (CH / TPH)      // 8 phases per chunk
#define LOG2E_K 1442.69504f // 1000 * log2(e)  (temp = 0.001)
#define WNEAR 26.0f         // saturation cutoff (|z|>=18 natural units)

// Fused soft-relay step (slow path): one rcp instead of two.
__device__ __forceinline__ void relay_step(float ka, float kb, float ku,
                                           float& aa, float& bb) {
    float z1 = fminf(ka - ku, 63.f);
    float z2 = fminf(ku - kb, 63.f);
    float e1 = __builtin_amdgcn_exp2f(z1);
    float e2 = __builtin_amdgcn_exp2f(z2);
    float p1 = 1.f + e1, p2 = 1.f + e2;
    float r  = __builtin_amdgcn_rcpf(p1 * p2);
    aa = (e2 - e1) * r;
    bb = (e1 * e2) * r;
}

__device__ __forceinline__ float wave_reduce_sum(float w) {
    #pragma unroll
    for (int off = 32; off > 0; off >>= 1)
        w += __shfl_down(w, off, 64);
    return w;
}

// ---------------- density MLP: [N,2] -> 16 -> 16 -> 16 -> 1 ----------------
__global__ __launch_bounds__(256) void density_kernel(
    const float* __restrict__ alpha, const float* __restrict__ beta,
    const float* __restrict__ w1, const float* __restrict__ b1,
    const float* __restrict__ w2, const float* __restrict__ b2,
    const float* __restrict__ w3, const float* __restrict__ b3,
    const float* __restrict__ w4, const float* __restrict__ b4,
    float* __restrict__ density_out, float* __restrict__ densum_parts)
{
    int n = blockIdx.x * 256 + threadIdx.x;
    bool valid = n < NM;
    int nn = valid ? n : NM - 1;
    float a = alpha[nn], b = beta[nn];

    float h1[16], h2[16], h3[16];
    #pragma unroll
    for (int j = 0; j < 16; j++) {
        float v = fmaf(a, w1[j], fmaf(b, w1[16 + j], b1[j]));
        h1[j] = fmaxf(v, 0.f);
    }
    #pragma unroll
    for (int j = 0; j < 16; j++) {
        float v = b2[j];
        #pragma unroll
        for (int k = 0; k < 16; k++) v = fmaf(h1[k], w2[k * 16 + j], v);
        h2[j] = fmaxf(v, 0.f);
    }
    #pragma unroll
    for (int j = 0; j < 16; j++) {
        float v = b3[j];
        #pragma unroll
        for (int k = 0; k < 16; k++) v = fmaf(h2[k], w3[k * 16 + j], v);
        h3[j] = fmaxf(v, 0.f);
    }
    float v = b4[0];
    #pragma unroll
    for (int k = 0; k < 16; k++) v = fmaf(h3[k], w4[k], v);
    float d = 1.f / (1.f + __expf(-v));

    if (valid) density_out[n] = d;
    float wsum = wave_reduce_sum(valid ? d : 0.f);
    __shared__ float ws_[4];
    if ((threadIdx.x & 63) == 0) ws_[threadIdx.x >> 6] = wsum;
    __syncthreads();
    if (threadIdx.x == 0)
        densum_parts[blockIdx.x] = ws_[0] + ws_[1] + ws_[2] + ws_[3];
}

// ---- pass 1: per-(n,chunk) affine composite over CH=128 steps -------------
__global__ __launch_bounds__(256) void chunk_compose_kernel(
    const float* __restrict__ x, const float* __restrict__ alpha,
    const float* __restrict__ beta,
    float* __restrict__ Abuf, float* __restrict__ Bbuf)
{
    __shared__ float xs[CH];
    int c = blockIdx.y;
    if (threadIdx.x < CH) xs[threadIdx.x] = x[c * CH + threadIdx.x] * LOG2E_K;
    __syncthreads();

    int n = blockIdx.x * 256 + threadIdx.x;
    int nn = (n < NM) ? n : NM - 1;
    float ka = alpha[nn] * LOG2E_K;
    float kb = beta[nn] * LOG2E_K;

    float A = 0.f, B = 1.f;
    for (int p = 0; p < NPH; p++) {
        float xr[TPH];
        #pragma unroll
        for (int j = 0; j < TPH; j++) xr[j] = xs[p * TPH + j];
        #pragma unroll
        for (int j = 0; j < TPH; j++) {
            float ku = xr[j];
            float d1 = ka - ku, d2 = ku - kb;
            bool nearb = fminf(fabsf(d1), fabsf(d2)) < WNEAR;
            if (__any(nearb)) {                  // wave-uniform branch
                float aa, bb;
                relay_step(ka, kb, ku, aa, bb);
                A = fmaf(bb, A, aa);
                B *= bb;
            } else {
                bool su = d1 < 0.f, sd = d2 < 0.f;
                A = su ? 1.f : (sd ? -1.f : A);
                B = (su || sd) ? 0.f : B;
            }
        }
    }
    if (n < NM) { Abuf[(size_t)c * NM + n] = A; Bbuf[(size_t)c * NM + n] = B; }
}

// ---- pass 2: sequential scan over the 32 chunk boundaries -----------------
__global__ __launch_bounds__(256) void chunk_scan_kernel(
    const float* __restrict__ init_raw,
    const float* __restrict__ Abuf, const float* __restrict__ Bbuf,
    float* __restrict__ sstart)
{
    int n = blockIdx.x * 256 + threadIdx.x;
    if (n >= NM) return;
    float s = tanhf(init_raw[n]);
    #pragma unroll 4
    for (int c = 0; c < NC; c++) {
        sstart[(size_t)c * NM + n] = s;             // state entering chunk c
        s = fmaf(Bbuf[(size_t)c * NM + n], s, Abuf[(size_t)c * NM + n]);
    }
}

// ---- pass 3: TWO independent recurrences per thread (n, n+256) ------------
// R9's counters: per-wave VALU issue ~5%, all pipes <40% -> latency-bound on
// per-wave serial chains. 2 chains/thread doubles independent work inside
// every stall window. 1280 blocks (grid 40x32), 20 waves/CU, 17.9 KB LDS.
// Barrier-free hot loop; per-wave LDS-tile reduce amortized over 2x n-work.
__global__ __launch_bounds__(256) void states_kernel(
    const float* __restrict__ x, const float* __restrict__ alpha,
    const float* __restrict__ beta, const float* __restrict__ density,
    const float* __restrict__ sstart,
    float* __restrict__ states, float* __restrict__ partials)
{
    __shared__ float xs[CH];
    __shared__ float tile[4 * 64 * (TPH + 1)];   // 17408 B

    int tid = threadIdx.x;
    int c = blockIdx.y;
    if (tid < CH) xs[tid] = x[c * CH + tid] * LOG2E_K;

    int n0 = blockIdx.x * 512 + tid;
    int n1 = n0 + 256;
    bool v0 = n0 < NM, v1 = n1 < NM;
    int nn0 = v0 ? n0 : NM - 1, nn1 = v1 ? n1 : NM - 1;
    float ka0 = alpha[nn0] * LOG2E_K, kb0 = beta[nn0] * LOG2E_K;
    float ka1 = alpha[nn1] * LOG2E_K, kb1 = beta[nn1] * LOG2E_K;
    float d0 = v0 ? density[n0] : 0.f, d1 = v1 ? density[n1] : 0.f;
    float s0 = sstart[(size_t)c * NM + nn0];
    float s1 = sstart[(size_t)c * NM + nn1];
    __syncthreads();   // once, for xs[]; hot loop below is barrier-free

    int wv = tid >> 6, ln = tid & 63;
    int tl = ln & 15, h = ln >> 4;
    float* wtile = &tile[wv * 64 * (TPH + 1)];
    float* tslot = &wtile[ln * (TPH + 1)];
    float* rowp0 = states + (size_t)c * CH * NM + n0;
    float* rowp1 = states + (size_t)c * CH * NM + n1;
    size_t prow  = (size_t)(blockIdx.x * 4 + wv) * TT + c * CH;

    for (int p = 0; p < NPH; p++) {
        float xr[TPH];
        #pragma unroll
        for (int j = 0; j < TPH; j++) xr[j] = xs[p * TPH + j];
        #pragma unroll
        for (int j = 0; j < TPH; j++) {
            float u = xr[j];
            float w10 = ka0 - u, w20 = u - kb0;
            float w11 = ka1 - u, w21 = u - kb1;
            float near0 = fminf(fabsf(w10), fabsf(w20));
            float near1 = fminf(fabsf(w11), fabsf(w21));
            if (__any(fminf(near0, near1) < WNEAR)) {   // wave-uniform
                float aa, bb;
                relay_step(ka0, kb0, u, aa, bb);
                s0 = fmaf(bb, s0, aa);
                relay_step(ka1, kb1, u, aa, bb);
                s1 = fmaf(bb, s1, aa);
            } else {
                s0 = (w10 < 0.f) ? 1.f : ((w20 < 0.f) ? -1.f : s0);
                s1 = (w11 < 0.f) ? 1.f : ((w21 < 0.f) ? -1.f : s1);
            }
            size_t roff = (size_t)(p * TPH + j) * NM;
            if (v0) rowp0[roff] = s0;
            if (v1) rowp1[roff] = s1;
            tslot[j] = fmaf(d0, s0, d1 * s1);   // fire-and-forget ds_write
        }
        // wait own LDS writes only (global stores stay in flight)
        asm volatile("s_waitcnt lgkmcnt(0)" ::: "memory");
        float acc = 0.f;
        #pragma unroll
        for (int k = 0; k < TPH; k++)
            acc += wtile[(h * 16 + k) * (TPH + 1) + tl];  // 2-way banks, free
        acc += __shfl_xor(acc, 16, 64);       // fold 4 n-groups
        acc += __shfl_xor(acc, 32, 64);
        if (ln < TPH) partials[prow + p * TPH + ln] = acc;
        // WAR guard before next phase overwrites the tile
        asm volatile("s_waitcnt lgkmcnt(0)" ::: "memory");
    }
}

// ---- pass 4: fold 160 wave-partials per t + 80 densum parts ---------------
__global__ __launch_bounds__(256) void finalize_kernel(
    const float* __restrict__ x, const float* __restrict__ partials,
    const float* __restrict__ densum_parts,
    const float* __restrict__ msr, const float* __restrict__ mor,
    const float* __restrict__ hsr, float* __restrict__ out)
{
    int t = blockIdx.x * 256 + threadIdx.x;
    if (t >= TT) return;
    float acc = 0.f;
    for (int r = 0; r < NPROW; r++)
        acc += partials[(size_t)r * TT + t];    // coalesced across lanes
    float dsum = 0.f;
    for (int bx = 0; bx < NBLK; bx++)
        dsum += densum_parts[bx];               // uniform -> scalar loads
    float sig_ms = 1.f / (1.f + __expf(-msr[0]));
    float sig_mo = 1.f / (1.f + __expf(-mor[0]));
    float sig_hs = 1.f / (1.f + __expf(-hsr[0]));
    float m_scale  = 10.f * sig_ms;
    float m_offset = fmaf(20.f, sig_mo, -10.f);
    float h_scale  = 10.f * sig_hs;
    float m = acc / dsum;
    out[t] = fmaf(m_scale, m, m_offset) + h_scale * x[t];
}

extern "C" void kernel_launch(void* const* d_in, const int* in_sizes, int n_in,
                              void* d_out, int out_size, void* d_ws, size_t ws_size,
                              hipStream_t stream)
{
    const float* x    = (const float*)d_in[0];   // [4096]
    const float* alpha= (const float*)d_in[1];   // [20301]
    const float* beta = (const float*)d_in[2];   // [20301]
    const float* init = (const float*)d_in[3];   // [20301]
    const float* msr  = (const float*)d_in[4];   // [1]
    const float* mor  = (const float*)d_in[5];   // [1]
    const float* hsr  = (const float*)d_in[6];   // [1]
    const float* w1   = (const float*)d_in[7];
    const float* b1   = (const float*)d_in[8];
    const float* w2   = (const float*)d_in[9];
    const float* b2   = (const float*)d_in[10];
    const float* w3   = (const float*)d_in[11];
    const float* b3   = (const float*)d_in[12];
    const float* w4   = (const float*)d_in[13];
    const float* b4   = (const float*)d_in[14];

    float* out     = (float*)d_out;          // [TT]
    float* density = out + TT;               // [NM]
    float* states  = density + NM;           // [TT*NM]

    // ws: densum_parts[80] | pad | sstart[NC*NM] | partials[NPROW*TT]
    float* densum_parts = (float*)d_ws;
    float* sstart       = densum_parts + 128;
    float* partials     = sstart + (size_t)NC * NM;

    // (A,B) chunk composites (2 x 2.6 MB) stashed in the states region of
    // d_out; fully consumed by chunk_scan before states overwrites.
    float* Abuf = states;
    float* Bbuf = states + (size_t)NC * NM;

    density_kernel<<<dim3(NBLK), dim3(256), 0, stream>>>(
        alpha, beta, w1, b1, w2, b2, w3, b3, w4, b4, density, densum_parts);

    chunk_compose_kernel<<<dim3(NBLK, NC), dim3(256), 0, stream>>>(
        x, alpha, beta, Abuf, Bbuf);

    chunk_scan_kernel<<<dim3(NBLK), dim3(256), 0, stream>>>(
        init, Abuf, Bbuf, sstart);

    states_kernel<<<dim3(SBLK, NC), dim3(256), 0, stream>>>(
        x, alpha, beta, density, sstart, states, partials);

    finalize_kernel<<<dim3(TT / 256), dim3(256), 0, stream>>>(
        x, partials, densum_parts, msr, mor, hsr, out);
}

// Round 11
// 452.594 us; speedup vs baseline: 1.3157x; 1.0058x over previous
//
#include <hip/hip_runtime.h>
#include <math.h>

// Problem constants
#define NM 20301            // mesh points
#define TT 4096             // time steps
#define NC 64               // t-chunks
#define CH 64               // steps per chunk = TT/NC
#define NBLK 80             // 256-thread n-kernels (density/compose/scan)
#define SBLK 20             // states blocks in n (1024 n per block, 4/thread)
#define NPROW (SBLK * 4)    // 80 per-wave partial rows
#define TPH 16              // t-phase width for fused reduce
#define NPH (CH / TPH)      // 4 phases per chunk
#define LOG2E_K 1442.69504f // 1000 * log2(e)  (temp = 0.001)
#define WNEAR 26.0f         // saturation cutoff (|z|>=18 natural units)

// Fused soft-relay step (slow path): one rcp instead of two.
__device__ __forceinline__ void relay_step(float ka, float kb, float ku,
                                           float& aa, float& bb) {
    float z1 = fminf(ka - ku, 63.f);
    float z2 = fminf(ku - kb, 63.f);
    float e1 = __builtin_amdgcn_exp2f(z1);
    float e2 = __builtin_amdgcn_exp2f(z2);
    float p1 = 1.f + e1, p2 = 1.f + e2;
    float r  = __builtin_amdgcn_rcpf(p1 * p2);
    aa = (e2 - e1) * r;
    bb = (e1 * e2) * r;
}

__device__ __forceinline__ float wave_reduce_sum(float w) {
    #pragma unroll
    for (int off = 32; off > 0; off >>= 1)
        w += __shfl_down(w, off, 64);
    return w;
}

// ---------------- density MLP: [N,2] -> 16 -> 16 -> 16 -> 1 ----------------
__global__ __launch_bounds__(256) void density_kernel(
    const float* __restrict__ alpha, const float* __restrict__ beta,
    const float* __restrict__ w1, const float* __restrict__ b1,
    const float* __restrict__ w2, const float* __restrict__ b2,
    const float* __restrict__ w3, const float* __restrict__ b3,
    const float* __restrict__ w4, const float* __restrict__ b4,
    float* __restrict__ density_out, float* __restrict__ densum_parts)
{
    int n = blockIdx.x * 256 + threadIdx.x;
    bool valid = n < NM;
    int nn = valid ? n : NM - 1;
    float a = alpha[nn], b = beta[nn];

    float h1[16], h2[16], h3[16];
    #pragma unroll
    for (int j = 0; j < 16; j++) {
        float v = fmaf(a, w1[j], fmaf(b, w1[16 + j], b1[j]));
        h1[j] = fmaxf(v, 0.f);
    }
    #pragma unroll
    for (int j = 0; j < 16; j++) {
        float v = b2[j];
        #pragma unroll
        for (int k = 0; k < 16; k++) v = fmaf(h1[k], w2[k * 16 + j], v);
        h2[j] = fmaxf(v, 0.f);
    }
    #pragma unroll
    for (int j = 0; j < 16; j++) {
        float v = b3[j];
        #pragma unroll
        for (int k = 0; k < 16; k++) v = fmaf(h2[k], w3[k * 16 + j], v);
        h3[j] = fmaxf(v, 0.f);
    }
    float v = b4[0];
    #pragma unroll
    for (int k = 0; k < 16; k++) v = fmaf(h3[k], w4[k], v);
    float d = 1.f / (1.f + __expf(-v));

    if (valid) density_out[n] = d;
    float wsum = wave_reduce_sum(valid ? d : 0.f);
    __shared__ float ws_[4];
    if ((threadIdx.x & 63) == 0) ws_[threadIdx.x >> 6] = wsum;
    __syncthreads();
    if (threadIdx.x == 0)
        densum_parts[blockIdx.x] = ws_[0] + ws_[1] + ws_[2] + ws_[3];
}

// ---- pass 1: per-(n,chunk) affine composite over CH=64 steps --------------
__global__ __launch_bounds__(256) void chunk_compose_kernel(
    const float* __restrict__ x, const float* __restrict__ alpha,
    const float* __restrict__ beta,
    float* __restrict__ Abuf, float* __restrict__ Bbuf)
{
    __shared__ float xs[CH];
    int c = blockIdx.y;
    if (threadIdx.x < CH) xs[threadIdx.x] = x[c * CH + threadIdx.x] * LOG2E_K;
    __syncthreads();

    int n = blockIdx.x * 256 + threadIdx.x;
    int nn = (n < NM) ? n : NM - 1;
    float ka = alpha[nn] * LOG2E_K;
    float kb = beta[nn] * LOG2E_K;

    float A = 0.f, B = 1.f;
    for (int p = 0; p < NPH; p++) {
        float xr[TPH];
        #pragma unroll
        for (int j = 0; j < TPH; j++) xr[j] = xs[p * TPH + j];
        #pragma unroll
        for (int j = 0; j < TPH; j++) {
            float ku = xr[j];
            float d1 = ka - ku, d2 = ku - kb;
            bool nearb = fminf(fabsf(d1), fabsf(d2)) < WNEAR;
            if (__any(nearb)) {                  // wave-uniform branch
                float aa, bb;
                relay_step(ka, kb, ku, aa, bb);
                A = fmaf(bb, A, aa);
                B *= bb;
            } else {
                bool su = d1 < 0.f, sd = d2 < 0.f;
                A = su ? 1.f : (sd ? -1.f : A);
                B = (su || sd) ? 0.f : B;
            }
        }
    }
    if (n < NM) { Abuf[(size_t)c * NM + n] = A; Bbuf[(size_t)c * NM + n] = B; }
}

// ---- pass 2: sequential scan over the 64 chunk boundaries -----------------
__global__ __launch_bounds__(256) void chunk_scan_kernel(
    const float* __restrict__ init_raw,
    const float* __restrict__ Abuf, const float* __restrict__ Bbuf,
    float* __restrict__ sstart)
{
    int n = blockIdx.x * 256 + threadIdx.x;
    if (n >= NM) return;
    float s = tanhf(init_raw[n]);
    #pragma unroll 4
    for (int c = 0; c < NC; c++) {
        sstart[(size_t)c * NM + n] = s;             // state entering chunk c
        s = fmaf(Bbuf[(size_t)c * NM + n], s, Abuf[(size_t)c * NM + n]);
    }
}

// ---- pass 3: FOUR independent recurrences per thread (n+{0,256,512,768}) --
// R10 proved the limiter is independent streams per SIMD; this doubles them
// again (4 chains x 20 waves/CU). The 4 chains' stores share one vaddr with
// 1024/2048/3072-B immediate offsets (13-bit signed limit). 1280 blocks
// (grid 20x64), all co-resident at 17.7 KB LDS; barrier-free hot loop.
__global__ __launch_bounds__(256) void states_kernel(
    const float* __restrict__ x, const float* __restrict__ alpha,
    const float* __restrict__ beta, const float* __restrict__ density,
    const float* __restrict__ sstart,
    float* __restrict__ states, float* __restrict__ partials)
{
    __shared__ float xs[CH];
    __shared__ float tile[4 * 64 * (TPH + 1)];   // 17408 B

    int tid = threadIdx.x;
    int c = blockIdx.y;
    if (tid < CH) xs[tid] = x[c * CH + tid] * LOG2E_K;

    int n0 = blockIdx.x * 1024 + tid;
    float s[4], d[4], ka[4], kb[4];
    bool v[4];
    #pragma unroll
    for (int q = 0; q < 4; q++) {
        int n = n0 + q * 256;
        v[q] = n < NM;
        int nn = v[q] ? n : NM - 1;
        ka[q] = alpha[nn] * LOG2E_K;
        kb[q] = beta[nn] * LOG2E_K;
        d[q]  = v[q] ? density[n] : 0.f;
        s[q]  = sstart[(size_t)c * NM + nn];
    }
    __syncthreads();   // once, for xs[]; hot loop below is barrier-free

    int wv = tid >> 6, ln = tid & 63;
    int tl = ln & 15, h = ln >> 4;
    float* wtile = &tile[wv * 64 * (TPH + 1)];
    float* tslot = &wtile[ln * (TPH + 1)];
    float* rp    = states + (size_t)c * CH * NM + n0;   // one vaddr, 4 chains
    size_t prow  = (size_t)(blockIdx.x * 4 + wv) * TT + c * CH;

    for (int p = 0; p < NPH; p++) {
        float xr[TPH];
        #pragma unroll
        for (int j = 0; j < TPH; j++) xr[j] = xs[p * TPH + j];
        #pragma unroll
        for (int j = 0; j < TPH; j++) {
            float u = xr[j];
            float w1_[4], w2_[4], nr[4];
            #pragma unroll
            for (int q = 0; q < 4; q++) {
                w1_[q] = ka[q] - u;
                w2_[q] = u - kb[q];
                nr[q]  = fminf(fabsf(w1_[q]), fabsf(w2_[q]));
            }
            float nmin = fminf(fminf(nr[0], nr[1]), fminf(nr[2], nr[3]));
            if (__any(nmin < WNEAR)) {           // wave-uniform branch
                #pragma unroll
                for (int q = 0; q < 4; q++) {
                    float aa, bb;
                    relay_step(ka[q], kb[q], u, aa, bb);
                    s[q] = fmaf(bb, s[q], aa);
                }
            } else {
                #pragma unroll
                for (int q = 0; q < 4; q++)
                    s[q] = (w1_[q] < 0.f) ? 1.f
                         : ((w2_[q] < 0.f) ? -1.f : s[q]);
            }
            #pragma unroll
            for (int q = 0; q < 4; q++)
                if (v[q]) rp[q * 256] = s[q];    // imm offsets off one vaddr
            rp += NM;
            tslot[j] = fmaf(d[0], s[0], fmaf(d[1], s[1],
                       fmaf(d[2], s[2], d[3] * s[3])));
        }
        // wait own LDS writes only (global stores stay in flight)
        asm volatile("s_waitcnt lgkmcnt(0)" ::: "memory");
        float acc = 0.f;
        #pragma unroll
        for (int k = 0; k < TPH; k++)
            acc += wtile[(h * 16 + k) * (TPH + 1) + tl];  // 2-way banks, free
        acc += __shfl_xor(acc, 16, 64);       // fold 4 n-groups
        acc += __shfl_xor(acc, 32, 64);
        if (ln < TPH) partials[prow + p * TPH + ln] = acc;
        // WAR guard before next phase overwrites the tile
        asm volatile("s_waitcnt lgkmcnt(0)" ::: "memory");
    }
}

// ---- pass 4: fold 80 wave-partials per t + 80 densum parts ----------------
__global__ __launch_bounds__(256) void finalize_kernel(
    const float* __restrict__ x, const float* __restrict__ partials,
    const float* __restrict__ densum_parts,
    const float* __restrict__ msr, const float* __restrict__ mor,
    const float* __restrict__ hsr, float* __restrict__ out)
{
    int t = blockIdx.x * 256 + threadIdx.x;
    if (t >= TT) return;
    float acc = 0.f;
    for (int r = 0; r < NPROW; r++)
        acc += partials[(size_t)r * TT + t];    // coalesced across lanes
    float dsum = 0.f;
    for (int bx = 0; bx < NBLK; bx++)
        dsum += densum_parts[bx];               // uniform -> scalar loads
    float sig_ms = 1.f / (1.f + __expf(-msr[0]));
    float sig_mo = 1.f / (1.f + __expf(-mor[0]));
    float sig_hs = 1.f / (1.f + __expf(-hsr[0]));
    float m_scale  = 10.f * sig_ms;
    float m_offset = fmaf(20.f, sig_mo, -10.f);
    float h_scale  = 10.f * sig_hs;
    float m = acc / dsum;
    out[t] = fmaf(m_scale, m, m_offset) + h_scale * x[t];
}

extern "C" void kernel_launch(void* const* d_in, const int* in_sizes, int n_in,
                              void* d_out, int out_size, void* d_ws, size_t ws_size,
                              hipStream_t stream)
{
    const float* x    = (const float*)d_in[0];   // [4096]
    const float* alpha= (const float*)d_in[1];   // [20301]
    const float* beta = (const float*)d_in[2];   // [20301]
    const float* init = (const float*)d_in[3];   // [20301]
    const float* msr  = (const float*)d_in[4];   // [1]
    const float* mor  = (const float*)d_in[5];   // [1]
    const float* hsr  = (const float*)d_in[6];   // [1]
    const float* w1   = (const float*)d_in[7];
    const float* b1   = (const float*)d_in[8];
    const float* w2   = (const float*)d_in[9];
    const float* b2   = (const float*)d_in[10];
    const float* w3   = (const float*)d_in[11];
    const float* b3   = (const float*)d_in[12];
    const float* w4   = (const float*)d_in[13];
    const float* b4   = (const float*)d_in[14];

    float* out     = (float*)d_out;          // [TT]
    float* density = out + TT;               // [NM]
    float* states  = density + NM;           // [TT*NM]

    // ws: densum_parts[80] | pad | sstart[NC*NM] | partials[NPROW*TT]
    float* densum_parts = (float*)d_ws;
    float* sstart       = densum_parts + 128;
    float* partials     = sstart + (size_t)NC * NM;

    // (A,B) chunk composites (2 x 5.2 MB) stashed in the states region of
    // d_out; fully consumed by chunk_scan before states overwrites.
    float* Abuf = states;
    float* Bbuf = states + (size_t)NC * NM;

    density_kernel<<<dim3(NBLK), dim3(256), 0, stream>>>(
        alpha, beta, w1, b1, w2, b2, w3, b3, w4, b4, density, densum_parts);

    chunk_compose_kernel<<<dim3(NBLK, NC), dim3(256), 0, stream>>>(
        x, alpha, beta, Abuf, Bbuf);

    chunk_scan_kernel<<<dim3(NBLK), dim3(256), 0, stream>>>(
        init, Abuf, Bbuf, sstart);

    states_kernel<<<dim3(SBLK, NC), dim3(256), 0, stream>>>(
        x, alpha, beta, density, sstart, states, partials);

    finalize_kernel<<<dim3(TT / 256), dim3(256), 0, stream>>>(
        x, partials, densum_parts, msr, mor, hsr, out);
}